// Round 9
// baseline (828.426 us; speedup 1.0000x reference)
//
#include <hip/hip_runtime.h>
#include <math.h>

// Problem constants (fixed by setup_inputs)
static constexpr int BATCH = 32;
static constexpr int NPRED = 512;   // outputs rows (LAP columns)
static constexpr int NTGT  = 200;   // targets rows (LAP rows)
static constexpr int DIM   = 768;
#define BIGF 1e9f                   // fresh-minv init (matches reference BIG)
#define QNANF __int_as_float(0x7fc00000)  // 'used' sentinel: NaN
// NaN-sentinel invariants (all exact): cur < NaN == false; NaN - delta == NaN;
// fminf(x, NaN) == x (C99); ballot(lval==wmin) excludes NaN lanes.
// R8 lesson: rectangular LAP duality needs v<=0 with v<0 only on matched
// columns -- column-reduction init is UNSOUND here. Round-0 algorithm only.

// ---------------------------------------------------------------------------
// Row squared-norms for BOTH inputs in one launch (round-0 config, verbatim).
// ---------------------------------------------------------------------------
__global__ __launch_bounds__(64) void norms_kernel(const float* __restrict__ O,
                                                   const float* __restrict__ T,
                                                   float* __restrict__ no_arr,
                                                   float* __restrict__ nt_arr) {
    int row = blockIdx.x;
    const float* src;
    float* dst;
    if (row < BATCH * NPRED) {
        src = O + (size_t)row * DIM;            dst = no_arr + row;
    } else {
        int r2 = row - BATCH * NPRED;
        src = T + (size_t)r2 * DIM;             dst = nt_arr + r2;
    }
    const float4* r = (const float4*)src;
    float s = 0.f;
#pragma unroll
    for (int k = 0; k < 3; ++k) {
        float4 v = r[threadIdx.x + 64 * k];
        s += v.x * v.x + v.y * v.y + v.z * v.z + v.w * v.w;
    }
#pragma unroll
    for (int off = 32; off; off >>= 1) s += __shfl_down(s, off);
    if (threadIdx.x == 0) *dst = s;
}

// ---------------------------------------------------------------------------
// cost[b][m][n] = sqrt(max(nt[m] + no[n] - 2 * dot(T[m], O[n]), 0))
// R15 structure kept (flat grid + batch-per-XCD remap + register prefetch).
// Same addresses / same k-ascending FMA chain -> cost bits unchanged.
// ---------------------------------------------------------------------------
__global__ __launch_bounds__(256) void cost_kernel(const float* __restrict__ O,
                                                   const float* __restrict__ T,
                                                   const float* __restrict__ no_arr,
                                                   const float* __restrict__ nt_arr,
                                                   float* __restrict__ cost) {
    const int wg  = blockIdx.x;          // 0..511
    const int xcd = wg & 7;
    const int idx = wg >> 3;             // 0..63
    const int b   = xcd + 8 * (idx >> 4);          // 4 batches per XCD
    const int t0  = idx & 15;                      // 16 tiles per batch
    const int n0  = (t0 & 7) * 64;
    const int m0  = (t0 >> 3) * 128;

    const float* Tb = T + (size_t)b * NTGT * DIM;
    const float* Ob = O + (size_t)b * NPRED * DIM;

    __shared__ __align__(16) float As[32][132];  // [k][m]
    __shared__ __align__(16) float Bs[32][68];   // [k][n]

    const int tid = threadIdx.x;
    const int tx = tid & 15;   // n/4
    const int ty = tid >> 4;   // m/8

    int arow[4], akk[4];
    const float* pA[4];
#pragma unroll
    for (int q = 0; q < 4; ++q) {
        int f = tid + q * 256;
        int r = f >> 3;
        int kk = (f & 7) << 2;
        int gm = m0 + r; if (gm > NTGT - 1) gm = NTGT - 1;
        arow[q] = r; akk[q] = kk;
        pA[q] = Tb + (size_t)gm * DIM + kk;
    }
    int brow[2], bkk[2];
    const float* pB[2];
#pragma unroll
    for (int q = 0; q < 2; ++q) {
        int f = tid + q * 256;
        int r = f >> 3;
        int kk = (f & 7) << 2;
        brow[q] = r; bkk[q] = kk;
        pB[q] = Ob + (size_t)(n0 + r) * DIM + kk;
    }

    float4 rA[4], rB[2];
#pragma unroll
    for (int q = 0; q < 4; ++q) rA[q] = *(const float4*)(pA[q]);
#pragma unroll
    for (int q = 0; q < 2; ++q) rB[q] = *(const float4*)(pB[q]);

    float acc[8][4] = {};

    for (int t = 0; t < DIM / 32; ++t) {
#pragma unroll
        for (int q = 0; q < 4; ++q) {
            As[akk[q] + 0][arow[q]] = rA[q].x;
            As[akk[q] + 1][arow[q]] = rA[q].y;
            As[akk[q] + 2][arow[q]] = rA[q].z;
            As[akk[q] + 3][arow[q]] = rA[q].w;
        }
#pragma unroll
        for (int q = 0; q < 2; ++q) {
            Bs[bkk[q] + 0][brow[q]] = rB[q].x;
            Bs[bkk[q] + 1][brow[q]] = rB[q].y;
            Bs[bkk[q] + 2][brow[q]] = rB[q].z;
            Bs[bkk[q] + 3][brow[q]] = rB[q].w;
        }
        __syncthreads();

        if (t + 1 < DIM / 32) {
            int k0n = (t + 1) * 32;
#pragma unroll
            for (int q = 0; q < 4; ++q) rA[q] = *(const float4*)(pA[q] + k0n);
#pragma unroll
            for (int q = 0; q < 2; ++q) rB[q] = *(const float4*)(pB[q] + k0n);
        }

#pragma unroll
        for (int k = 0; k < 32; ++k) {
            float4 a0 = *(const float4*)&As[k][ty * 8];
            float4 a1 = *(const float4*)&As[k][ty * 8 + 4];
            float4 bv = *(const float4*)&Bs[k][tx * 4];
            float av[8] = {a0.x, a0.y, a0.z, a0.w, a1.x, a1.y, a1.z, a1.w};
#pragma unroll
            for (int i = 0; i < 8; ++i) {
                acc[i][0] += av[i] * bv.x; acc[i][1] += av[i] * bv.y;
                acc[i][2] += av[i] * bv.z; acc[i][3] += av[i] * bv.w;
            }
        }
        __syncthreads();
    }

    {
        float4 nov = *(const float4*)(no_arr + b * NPRED + n0 + (tx << 2));
#pragma unroll
        for (int i = 0; i < 8; ++i) {
            int gm = m0 + ty * 8 + i;
            if (gm < NTGT) {
                float ntv = nt_arr[b * NTGT + gm];
                float4 o;
                o.x = sqrtf(fmaxf(ntv + nov.x - 2.0f * acc[i][0], 0.0f));
                o.y = sqrtf(fmaxf(ntv + nov.y - 2.0f * acc[i][1], 0.0f));
                o.z = sqrtf(fmaxf(ntv + nov.z - 2.0f * acc[i][2], 0.0f));
                o.w = sqrtf(fmaxf(ntv + nov.w - 2.0f * acc[i][3], 0.0f));
                *(float4*)&cost[((size_t)b * NTGT + gm) * NPRED + n0 + (tx << 2)] = o;
            }
        }
    }
}

// ---------------------------------------------------------------------------
// LAP helpers (round-0 verbatim)
// ---------------------------------------------------------------------------
__device__ __forceinline__ int rl(int v, int l) {
    return __builtin_amdgcn_readlane(v, l);
}
__device__ __forceinline__ float rlf(float v, int l) {
    return __int_as_float(__builtin_amdgcn_readlane(__float_as_int(v), l));
}
__device__ __forceinline__ int sel8i(const int* a, int s) {
    int r = a[0];
#pragma unroll
    for (int k = 1; k < 8; ++k) r = (s == k) ? a[k] : r;
    return r;
}
__device__ __forceinline__ float sel8f(const float* a, int s) {
    float r = a[0];
#pragma unroll
    for (int k = 1; k < 8; ++k) r = (s == k) ? a[k] : r;
    return r;
}
// Wave-wide min via DPP (VALU-only): lane 63 ends with min of all 64 lanes.
// fminf skips NaN (returns the number) -> used cols drop out naturally.
__device__ __forceinline__ float dpp_min_f32(float x) {
    float t;
    t = __int_as_float(__builtin_amdgcn_update_dpp(__float_as_int(x), __float_as_int(x), 0x111, 0xF, 0xF, false)); x = fminf(x, t);
    t = __int_as_float(__builtin_amdgcn_update_dpp(__float_as_int(x), __float_as_int(x), 0x112, 0xF, 0xF, false)); x = fminf(x, t);
    t = __int_as_float(__builtin_amdgcn_update_dpp(__float_as_int(x), __float_as_int(x), 0x114, 0xF, 0xF, false)); x = fminf(x, t);
    t = __int_as_float(__builtin_amdgcn_update_dpp(__float_as_int(x), __float_as_int(x), 0x118, 0xF, 0xF, false)); x = fminf(x, t);
    t = __int_as_float(__builtin_amdgcn_update_dpp(__float_as_int(x), __float_as_int(x), 0x142, 0xF, 0xF, false)); x = fminf(x, t);
    t = __int_as_float(__builtin_amdgcn_update_dpp(__float_as_int(x), __float_as_int(x), 0x143, 0xF, 0xF, false)); x = fminf(x, t);
    return x;
}
// NaN-safe lane-local argmin tree over 8 values (tie -> lower q; NaN loses).
// node: m = fminf(a,b); pick qa iff m==a (ties -> first; a==NaN -> false).
__device__ __forceinline__ float tree8n(const float* m, int& lq) {
    float v01 = fminf(m[0], m[1]); int q01 = (v01 == m[0]) ? 0 : 1;
    float v23 = fminf(m[2], m[3]); int q23 = (v23 == m[2]) ? 2 : 3;
    float v45 = fminf(m[4], m[5]); int q45 = (v45 == m[4]) ? 4 : 5;
    float v67 = fminf(m[6], m[7]); int q67 = (v67 == m[6]) ? 6 : 7;
    float v03 = fminf(v01, v23);   int q03 = (v03 == v01) ? q01 : q23;
    float v47 = fminf(v45, v67);   int q47 = (v47 == v45) ? q45 : q67;
    float r = fminf(v03, v47);     lq = (r == v03) ? q03 : q47;
    return r;
}

// ---------------------------------------------------------------------------
// Jonker-Volgenant LAP, one wave per batch -- ROUND-0 ALGORITHM, with one
// bit-exact ISSUE-ORDER change (round 19): the runner-up speculation block
// (~25 instr incl. 6 dependent DPPs) used to sit between the argmin result
// and the dual updates. The next scan depends only on ca/cb (a register copy
// on spec-hit) and minv/v -- so on every spec-hit pop those ~50 issue-cycles
// were pure added critical-path latency. The spec results (sa/sb/spec_j) are
// not consumed until the NEXT pop's load decision. Moved: demand load issue
// -> dual updates -> spec. Spec reads only saved values (lval, psel; ordering
// invariant under the uniform minv shift), so this is a pure reorder --
// trajectory and bits 100% unchanged. col = lane*8 + q.
// ---------------------------------------------------------------------------
__global__ __launch_bounds__(64) void lap_kernel(const float* __restrict__ cost,
                                                 int* __restrict__ out) {
    const int b = blockIdx.x;
    const int lane = threadIdx.x;
    const float* C = cost + (size_t)b * NTGT * NPRED;
    const float* Cl = C + lane * 8;       // lane's 8-column slice base

    __shared__ float u0[NTGT + 1];        // row duals (stable during a row-step)
    __shared__ int g2p[NTGT];

    for (int k = lane; k < NTGT + 1; k += 64) u0[k] = 0.f;

    float v[8], minv[8], up[8];
    int p_arr[8], way_arr[8];
#pragma unroll
    for (int q = 0; q < 8; ++q) {
        v[q] = 0.f; up[q] = 0.f; p_arr[q] = 0; way_arr[q] = 0;
    }
    __syncthreads();

    float4 ca = *(const float4*)(Cl);         // prefetch row 0 (row-step i=1)
    float4 cb = *(const float4*)(Cl + 4);
    float4 sa = ca, sb = cb;                  // speculative shadow regs

    for (int i = 1; i <= NTGT; ++i) {
#pragma unroll
        for (int q = 0; q < 8; ++q) minv[q] = BIGF;
        float uI = 0.f;       // u[i] accumulator (virtual col 0), uniform
        float u_i0 = 0.f;     // u of current scan row (row i starts at 0)
        int j0 = 0;
        int j1 = 0;
        int spec_j = 0;       // predicted next winner column (1-based)

        for (int it = 0; it <= NPRED; ++it) {
            float c[8];
            c[0] = ca.x; c[1] = ca.y; c[2] = ca.z; c[3] = ca.w;
            c[4] = cb.x; c[5] = cb.y; c[6] = cb.z; c[7] = cb.w;

            // scan row i0: reduced cost, same float order as reference.
            // used cols have minv == NaN: cur < NaN is false -> inert.
            bool used_b[8];
#pragma unroll
            for (int q = 0; q < 8; ++q) {
                used_b[q] = __builtin_isnan(minv[q]);
                float cur = (c[q] - u_i0) - v[q];
                bool imp = cur < minv[q];
                minv[q] = imp ? cur : minv[q];
                way_arr[q] = imp ? j0 : way_arr[q];
            }

            // primary argmin (exact; tie -> lowest column; NaN drops out)
            int lq;
            float lval = tree8n(minv, lq);
            int   psel = sel8i(p_arr, lq);
            float usel = sel8f(up, lq);
            float wmin = rlf(dpp_min_f32(lval), 63);
            unsigned long long mask = __ballot(lval == wmin);
            int w = (int)__builtin_ctzll(mask);
            int qw  = rl(lq, w);
            int i0n = rl(psel, w);              // p[j1]
            float u_n = rlf(usel, w);           // u0[p[j1]] (start-of-row value)
            float delta = wmin;
            j1 = w * 8 + qw + 1;
            bool done = (i0n == 0);

            // demand / hit load for the row we must scan next -- ISSUE FIRST
            if (!done) {
                if (j1 == spec_j) {
                    ca = sa; cb = sb;           // shadow load already complete
                } else {
                    const float* Crow = Cl + (size_t)(i0n - 1) * NPRED;
                    ca = *(const float4*)(Crow);
                    cb = *(const float4*)(Crow + 4);
                }
            }

            // dual updates NEXT (reference order; j1 not yet marked used).
            // These feed the next scan's critical path -- ahead of spec now.
            // x +/- 0.0f is bit-exact; NaN - delta == NaN keeps used cols inert.
            uI += delta;
#pragma unroll
            for (int q = 0; q < 8; ++q) {
                float d0 = used_b[q] ? delta : 0.f;
                v[q]  -= d0;
                up[q] += d0;
                minv[q] -= delta;
            }
            // mark j1 used
            {
                bool lw = (lane == w);
#pragma unroll
                for (int q = 0; q < 8; ++q)
                    minv[q] = (lw && q == qw) ? QNANF : minv[q];
            }

            // runner-up speculation LAST (results consumed only next pop;
            // uniform minv shift preserves ordering among old candidates)
            if (!done) {
                float lv2 = (lane == w) ? QNANF : lval;
                float wm2 = rlf(dpp_min_f32(lv2), 63);
                unsigned long long m2 = __ballot(lv2 == wm2);
                int w2 = (int)__builtin_ctzll(m2);
                int q2 = rl(lq, w2);
                int p2 = rl(psel, w2);
                int sj = w2 * 8 + q2 + 1;
                if (p2 != 0 && sj != spec_j) {
                    const float* Srow = Cl + (size_t)(p2 - 1) * NPRED;
                    sa = *(const float4*)(Srow);
                    sb = *(const float4*)(Srow + 4);
                }
                spec_j = sj;   // if p2==0, a hit implies done (data unused)
            }

            if (done) break;
            u_i0 = u_n;
            j0 = j1;
        }

        // prefetch next row-step's first scan row (row i, 0-based)
        if (i < NTGT) {
            const float* Crow = Cl + (size_t)i * NPRED;
            ca = *(const float4*)(Crow);
            cb = *(const float4*)(Crow + 4);
        }

        // write back u (pre-augment p): used cols carry u0[p]+deltas in up[]
#pragma unroll
        for (int q = 0; q < 8; ++q) {
            bool usedq = __builtin_isnan(minv[q]);
            if (usedq && p_arr[q] != 0) u0[p_arr[q]] = up[q];
        }
        if (lane == 0) u0[i] = uI;

        // backtrack augmenting path (uniform scalar walk over registers)
        {
            int j = j1;
            for (int s = 0; s <= NPRED; ++s) {
                int ow = (j - 1) >> 3, oq = (j - 1) & 7;
                int wj = rl(sel8i(way_arr, oq), ow);    // way[j]
                int pOfW;
                if (wj == 0) {
                    pOfW = i;                           // p[0] = i (virtual)
                } else {
                    int ow2 = (wj - 1) >> 3, oq2 = (wj - 1) & 7;
                    pOfW = rl(sel8i(p_arr, oq2), ow2);  // old p[way[j]]
                }
#pragma unroll
                for (int q = 0; q < 8; ++q) {
                    bool mine = (lane == ow) && (q == oq);
                    p_arr[q] = mine ? pOfW : p_arr[q];
                }
                if (wj == 0) break;
                j = wj;
            }
        }

        __syncthreads();  // u0 write-back visible before refresh reads
        // refresh up = u0[p[col]] with post-augment p
#pragma unroll
        for (int q = 0; q < 8; ++q) up[q] = u0[p_arr[q]];
    }

    // invert matching: g2p[row] = col (0-based pred index)
#pragma unroll
    for (int q = 0; q < 8; ++q) {
        int r = p_arr[q];
        if (r > 0) g2p[r - 1] = lane * 8 + q;
    }
    __syncthreads();

    // sort by pred index via rank counting (values distinct)
    for (int t = lane; t < NTGT; t += 64) {
        int myv = g2p[t];
        int rank = 0;
        for (int l = 0; l < NTGT; ++l) rank += (g2p[l] < myv) ? 1 : 0;
        out[b * 2 * NTGT + rank] = myv;          // index_i: sorted pred indices
        out[b * 2 * NTGT + NTGT + rank] = t;     // index_j: gt index (argsort)
    }
}

extern "C" void kernel_launch(void* const* d_in, const int* in_sizes, int n_in,
                              void* d_out, int out_size, void* d_ws, size_t ws_size,
                              hipStream_t stream) {
    const float* outputs = (const float*)d_in[0];  // [32, 512, 768]
    const float* targets = (const float*)d_in[1];  // [32, 200, 768]
    int* out = (int*)d_out;                        // [32, 2, 200] int32

    float* cost   = (float*)d_ws;                         // [32][200][512]
    float* no_arr = cost + (size_t)BATCH * NTGT * NPRED;  // [32*512]
    float* nt_arr = no_arr + (size_t)BATCH * NPRED;       // [32*200]

    norms_kernel<<<BATCH * (NPRED + NTGT), 64, 0, stream>>>(outputs, targets,
                                                            no_arr, nt_arr);
    cost_kernel<<<512, 256, 0, stream>>>(outputs, targets, no_arr, nt_arr, cost);
    lap_kernel<<<BATCH, 64, 0, stream>>>(cost, out);
}

// Round 10
// 760.916 us; speedup vs baseline: 1.0887x; 1.0887x over previous
//
#include <hip/hip_runtime.h>
#include <math.h>

// Problem constants (fixed by setup_inputs)
static constexpr int BATCH = 32;
static constexpr int NPRED = 512;   // outputs rows (LAP columns)
static constexpr int NTGT  = 200;   // targets rows (LAP rows)
static constexpr int DIM   = 768;
#define BIGF 1e9f                   // fresh-minv init (matches reference BIG)
#define QNANF __int_as_float(0x7fc00000)  // 'used' sentinel: NaN
// NaN-sentinel invariants (all exact): cur < NaN == false; NaN - delta == NaN;
// fminf(x, NaN) == x (C99); ballot(lval==wmin) excludes NaN lanes.
// SESSION LEDGER (do not retry): lap-side LDS row cache (+20%), carried-
// payload argmin (+6%), XCD co-location (0, FETCH unchanged), greedy row
// init (+4%, pops conserved), column-reduction init (UNSOUND: rectangular
// duality needs v<=0), issue-order motion (+11%, branch/schedule damage).
// lap is a latency-chain floor: ~3500 serial pops x ~400cyc, 1 wave/CU.

// ---------------------------------------------------------------------------
// Row squared-norms for BOTH inputs in one launch (round-0 config, verbatim).
// ---------------------------------------------------------------------------
__global__ __launch_bounds__(64) void norms_kernel(const float* __restrict__ O,
                                                   const float* __restrict__ T,
                                                   float* __restrict__ no_arr,
                                                   float* __restrict__ nt_arr) {
    int row = blockIdx.x;
    const float* src;
    float* dst;
    if (row < BATCH * NPRED) {
        src = O + (size_t)row * DIM;            dst = no_arr + row;
    } else {
        int r2 = row - BATCH * NPRED;
        src = T + (size_t)r2 * DIM;             dst = nt_arr + r2;
    }
    const float4* r = (const float4*)src;
    float s = 0.f;
#pragma unroll
    for (int k = 0; k < 3; ++k) {
        float4 v = r[threadIdx.x + 64 * k];
        s += v.x * v.x + v.y * v.y + v.z * v.z + v.w * v.w;
    }
#pragma unroll
    for (int off = 32; off; off >>= 1) s += __shfl_down(s, off);
    if (threadIdx.x == 0) *dst = s;
}

// ---------------------------------------------------------------------------
// cost[b][m][n] = sqrt(max(nt[m] + no[n] - 2 * dot(T[m], O[n]), 0))
// Best-measured config (R5, 762.8us total): flat grid + batch-per-XCD remap
// + register prefetch. Same addresses / same k-ascending FMA chain as round-0
// -> cost bits unchanged.
// ---------------------------------------------------------------------------
__global__ __launch_bounds__(256) void cost_kernel(const float* __restrict__ O,
                                                   const float* __restrict__ T,
                                                   const float* __restrict__ no_arr,
                                                   const float* __restrict__ nt_arr,
                                                   float* __restrict__ cost) {
    const int wg  = blockIdx.x;          // 0..511
    const int xcd = wg & 7;
    const int idx = wg >> 3;             // 0..63
    const int b   = xcd + 8 * (idx >> 4);          // 4 batches per XCD
    const int t0  = idx & 15;                      // 16 tiles per batch
    const int n0  = (t0 & 7) * 64;
    const int m0  = (t0 >> 3) * 128;

    const float* Tb = T + (size_t)b * NTGT * DIM;
    const float* Ob = O + (size_t)b * NPRED * DIM;

    __shared__ __align__(16) float As[32][132];  // [k][m]
    __shared__ __align__(16) float Bs[32][68];   // [k][n]

    const int tid = threadIdx.x;
    const int tx = tid & 15;   // n/4
    const int ty = tid >> 4;   // m/8

    int arow[4], akk[4];
    const float* pA[4];
#pragma unroll
    for (int q = 0; q < 4; ++q) {
        int f = tid + q * 256;
        int r = f >> 3;
        int kk = (f & 7) << 2;
        int gm = m0 + r; if (gm > NTGT - 1) gm = NTGT - 1;
        arow[q] = r; akk[q] = kk;
        pA[q] = Tb + (size_t)gm * DIM + kk;
    }
    int brow[2], bkk[2];
    const float* pB[2];
#pragma unroll
    for (int q = 0; q < 2; ++q) {
        int f = tid + q * 256;
        int r = f >> 3;
        int kk = (f & 7) << 2;
        brow[q] = r; bkk[q] = kk;
        pB[q] = Ob + (size_t)(n0 + r) * DIM + kk;
    }

    float4 rA[4], rB[2];
#pragma unroll
    for (int q = 0; q < 4; ++q) rA[q] = *(const float4*)(pA[q]);
#pragma unroll
    for (int q = 0; q < 2; ++q) rB[q] = *(const float4*)(pB[q]);

    float acc[8][4] = {};

    for (int t = 0; t < DIM / 32; ++t) {
#pragma unroll
        for (int q = 0; q < 4; ++q) {
            As[akk[q] + 0][arow[q]] = rA[q].x;
            As[akk[q] + 1][arow[q]] = rA[q].y;
            As[akk[q] + 2][arow[q]] = rA[q].z;
            As[akk[q] + 3][arow[q]] = rA[q].w;
        }
#pragma unroll
        for (int q = 0; q < 2; ++q) {
            Bs[bkk[q] + 0][brow[q]] = rB[q].x;
            Bs[bkk[q] + 1][brow[q]] = rB[q].y;
            Bs[bkk[q] + 2][brow[q]] = rB[q].z;
            Bs[bkk[q] + 3][brow[q]] = rB[q].w;
        }
        __syncthreads();

        if (t + 1 < DIM / 32) {
            int k0n = (t + 1) * 32;
#pragma unroll
            for (int q = 0; q < 4; ++q) rA[q] = *(const float4*)(pA[q] + k0n);
#pragma unroll
            for (int q = 0; q < 2; ++q) rB[q] = *(const float4*)(pB[q] + k0n);
        }

#pragma unroll
        for (int k = 0; k < 32; ++k) {
            float4 a0 = *(const float4*)&As[k][ty * 8];
            float4 a1 = *(const float4*)&As[k][ty * 8 + 4];
            float4 bv = *(const float4*)&Bs[k][tx * 4];
            float av[8] = {a0.x, a0.y, a0.z, a0.w, a1.x, a1.y, a1.z, a1.w};
#pragma unroll
            for (int i = 0; i < 8; ++i) {
                acc[i][0] += av[i] * bv.x; acc[i][1] += av[i] * bv.y;
                acc[i][2] += av[i] * bv.z; acc[i][3] += av[i] * bv.w;
            }
        }
        __syncthreads();
    }

    {
        float4 nov = *(const float4*)(no_arr + b * NPRED + n0 + (tx << 2));
#pragma unroll
        for (int i = 0; i < 8; ++i) {
            int gm = m0 + ty * 8 + i;
            if (gm < NTGT) {
                float ntv = nt_arr[b * NTGT + gm];
                float4 o;
                o.x = sqrtf(fmaxf(ntv + nov.x - 2.0f * acc[i][0], 0.0f));
                o.y = sqrtf(fmaxf(ntv + nov.y - 2.0f * acc[i][1], 0.0f));
                o.z = sqrtf(fmaxf(ntv + nov.z - 2.0f * acc[i][2], 0.0f));
                o.w = sqrtf(fmaxf(ntv + nov.w - 2.0f * acc[i][3], 0.0f));
                *(float4*)&cost[((size_t)b * NTGT + gm) * NPRED + n0 + (tx << 2)] = o;
            }
        }
    }
}

// ---------------------------------------------------------------------------
// LAP helpers (round-0 verbatim)
// ---------------------------------------------------------------------------
__device__ __forceinline__ int rl(int v, int l) {
    return __builtin_amdgcn_readlane(v, l);
}
__device__ __forceinline__ float rlf(float v, int l) {
    return __int_as_float(__builtin_amdgcn_readlane(__float_as_int(v), l));
}
__device__ __forceinline__ int sel8i(const int* a, int s) {
    int r = a[0];
#pragma unroll
    for (int k = 1; k < 8; ++k) r = (s == k) ? a[k] : r;
    return r;
}
__device__ __forceinline__ float sel8f(const float* a, int s) {
    float r = a[0];
#pragma unroll
    for (int k = 1; k < 8; ++k) r = (s == k) ? a[k] : r;
    return r;
}
// Wave-wide min via DPP (VALU-only): lane 63 ends with min of all 64 lanes.
// fminf skips NaN (returns the number) -> used cols drop out naturally.
__device__ __forceinline__ float dpp_min_f32(float x) {
    float t;
    t = __int_as_float(__builtin_amdgcn_update_dpp(__float_as_int(x), __float_as_int(x), 0x111, 0xF, 0xF, false)); x = fminf(x, t);
    t = __int_as_float(__builtin_amdgcn_update_dpp(__float_as_int(x), __float_as_int(x), 0x112, 0xF, 0xF, false)); x = fminf(x, t);
    t = __int_as_float(__builtin_amdgcn_update_dpp(__float_as_int(x), __float_as_int(x), 0x114, 0xF, 0xF, false)); x = fminf(x, t);
    t = __int_as_float(__builtin_amdgcn_update_dpp(__float_as_int(x), __float_as_int(x), 0x118, 0xF, 0xF, false)); x = fminf(x, t);
    t = __int_as_float(__builtin_amdgcn_update_dpp(__float_as_int(x), __float_as_int(x), 0x142, 0xF, 0xF, false)); x = fminf(x, t);
    t = __int_as_float(__builtin_amdgcn_update_dpp(__float_as_int(x), __float_as_int(x), 0x143, 0xF, 0xF, false)); x = fminf(x, t);
    return x;
}
// NaN-safe lane-local argmin tree over 8 values (tie -> lower q; NaN loses).
// node: m = fminf(a,b); pick qa iff m==a (ties -> first; a==NaN -> false).
__device__ __forceinline__ float tree8n(const float* m, int& lq) {
    float v01 = fminf(m[0], m[1]); int q01 = (v01 == m[0]) ? 0 : 1;
    float v23 = fminf(m[2], m[3]); int q23 = (v23 == m[2]) ? 2 : 3;
    float v45 = fminf(m[4], m[5]); int q45 = (v45 == m[4]) ? 4 : 5;
    float v67 = fminf(m[6], m[7]); int q67 = (v67 == m[6]) ? 6 : 7;
    float v03 = fminf(v01, v23);   int q03 = (v03 == v01) ? q01 : q23;
    float v47 = fminf(v45, v67);   int q47 = (v47 == v45) ? q45 : q67;
    float r = fminf(v03, v47);     lq = (r == v03) ? q03 : q47;
    return r;
}

// ---------------------------------------------------------------------------
// Jonker-Volgenant LAP, one wave per batch, zero barriers/LDS in the Dijkstra
// iteration. ROUND-0 VERBATIM (best measured: 579-582us across 4 runs).
// Bit-exact reference trajectory (absmax 0). Six optimization attempts from
// all angles regressed or were neutral (see ledger at top) -- this loop is a
// sharp local optimum; the kernel is latency-chain-bound, not mem/compute
// bound. col = lane*8 + q.
// ---------------------------------------------------------------------------
__global__ __launch_bounds__(64) void lap_kernel(const float* __restrict__ cost,
                                                 int* __restrict__ out) {
    const int b = blockIdx.x;
    const int lane = threadIdx.x;
    const float* C = cost + (size_t)b * NTGT * NPRED;
    const float* Cl = C + lane * 8;       // lane's 8-column slice base

    __shared__ float u0[NTGT + 1];        // row duals (stable during a row-step)
    __shared__ int g2p[NTGT];

    for (int k = lane; k < NTGT + 1; k += 64) u0[k] = 0.f;

    float v[8], minv[8], up[8];
    int p_arr[8], way_arr[8];
#pragma unroll
    for (int q = 0; q < 8; ++q) {
        v[q] = 0.f; up[q] = 0.f; p_arr[q] = 0; way_arr[q] = 0;
    }
    __syncthreads();

    float4 ca = *(const float4*)(Cl);         // prefetch row 0 (row-step i=1)
    float4 cb = *(const float4*)(Cl + 4);
    float4 sa = ca, sb = cb;                  // speculative shadow regs

    for (int i = 1; i <= NTGT; ++i) {
#pragma unroll
        for (int q = 0; q < 8; ++q) minv[q] = BIGF;
        float uI = 0.f;       // u[i] accumulator (virtual col 0), uniform
        float u_i0 = 0.f;     // u of current scan row (row i starts at 0)
        int j0 = 0;
        int j1 = 0;
        int spec_j = 0;       // predicted next winner column (1-based)

        for (int it = 0; it <= NPRED; ++it) {
            float c[8];
            c[0] = ca.x; c[1] = ca.y; c[2] = ca.z; c[3] = ca.w;
            c[4] = cb.x; c[5] = cb.y; c[6] = cb.z; c[7] = cb.w;

            // scan row i0: reduced cost, same float order as reference.
            // used cols have minv == NaN: cur < NaN is false -> inert.
            bool used_b[8];
#pragma unroll
            for (int q = 0; q < 8; ++q) {
                used_b[q] = __builtin_isnan(minv[q]);
                float cur = (c[q] - u_i0) - v[q];
                bool imp = cur < minv[q];
                minv[q] = imp ? cur : minv[q];
                way_arr[q] = imp ? j0 : way_arr[q];
            }

            // primary argmin (exact; tie -> lowest column; NaN drops out)
            int lq;
            float lval = tree8n(minv, lq);
            int   psel = sel8i(p_arr, lq);
            float usel = sel8f(up, lq);
            float wmin = rlf(dpp_min_f32(lval), 63);
            unsigned long long mask = __ballot(lval == wmin);
            int w = (int)__builtin_ctzll(mask);
            int qw  = rl(lq, w);
            int i0n = rl(psel, w);              // p[j1]
            float u_n = rlf(usel, w);           // u0[p[j1]] (start-of-row value)
            float delta = wmin;
            j1 = w * 8 + qw + 1;
            bool done = (i0n == 0);

            if (!done) {
                // demand / hit for the row we must scan next
                if (j1 == spec_j) {
                    ca = sa; cb = sb;           // shadow load already complete
                } else {
                    const float* Crow = Cl + (size_t)(i0n - 1) * NPRED;
                    ca = *(const float4*)(Crow);
                    cb = *(const float4*)(Crow + 4);
                }
                // cheap runner-up speculation for the NEXT iteration, issued
                // before the dual updates (maximum latency cover). Uniform
                // minv shift preserves ordering among old candidates.
                float lv2 = (lane == w) ? QNANF : lval;
                float wm2 = rlf(dpp_min_f32(lv2), 63);
                unsigned long long m2 = __ballot(lv2 == wm2);
                int w2 = (int)__builtin_ctzll(m2);
                int q2 = rl(lq, w2);
                int p2 = rl(psel, w2);
                int sj = w2 * 8 + q2 + 1;
                if (p2 != 0 && sj != spec_j) {
                    const float* Srow = Cl + (size_t)(p2 - 1) * NPRED;
                    sa = *(const float4*)(Srow);
                    sb = *(const float4*)(Srow + 4);
                }
                spec_j = sj;   // if p2==0, a hit implies done (data unused)
            }

            // dual updates (reference order; j1 not yet marked used).
            // x +/- 0.0f is bit-exact; NaN - delta == NaN keeps used cols inert.
            uI += delta;
#pragma unroll
            for (int q = 0; q < 8; ++q) {
                float d0 = used_b[q] ? delta : 0.f;
                v[q]  -= d0;
                up[q] += d0;
                minv[q] -= delta;
            }
            // mark j1 used
            {
                bool lw = (lane == w);
#pragma unroll
                for (int q = 0; q < 8; ++q)
                    minv[q] = (lw && q == qw) ? QNANF : minv[q];
            }

            if (done) break;
            u_i0 = u_n;
            j0 = j1;
        }

        // prefetch next row-step's first scan row (row i, 0-based)
        if (i < NTGT) {
            const float* Crow = Cl + (size_t)i * NPRED;
            ca = *(const float4*)(Crow);
            cb = *(const float4*)(Crow + 4);
        }

        // write back u (pre-augment p): used cols carry u0[p]+deltas in up[]
#pragma unroll
        for (int q = 0; q < 8; ++q) {
            bool usedq = __builtin_isnan(minv[q]);
            if (usedq && p_arr[q] != 0) u0[p_arr[q]] = up[q];
        }
        if (lane == 0) u0[i] = uI;

        // backtrack augmenting path (uniform scalar walk over registers)
        {
            int j = j1;
            for (int s = 0; s <= NPRED; ++s) {
                int ow = (j - 1) >> 3, oq = (j - 1) & 7;
                int wj = rl(sel8i(way_arr, oq), ow);    // way[j]
                int pOfW;
                if (wj == 0) {
                    pOfW = i;                           // p[0] = i (virtual)
                } else {
                    int ow2 = (wj - 1) >> 3, oq2 = (wj - 1) & 7;
                    pOfW = rl(sel8i(p_arr, oq2), ow2);  // old p[way[j]]
                }
#pragma unroll
                for (int q = 0; q < 8; ++q) {
                    bool mine = (lane == ow) && (q == oq);
                    p_arr[q] = mine ? pOfW : p_arr[q];
                }
                if (wj == 0) break;
                j = wj;
            }
        }

        __syncthreads();  // u0 write-back visible before refresh reads
        // refresh up = u0[p[col]] with post-augment p
#pragma unroll
        for (int q = 0; q < 8; ++q) up[q] = u0[p_arr[q]];
    }

    // invert matching: g2p[row] = col (0-based pred index)
#pragma unroll
    for (int q = 0; q < 8; ++q) {
        int r = p_arr[q];
        if (r > 0) g2p[r - 1] = lane * 8 + q;
    }
    __syncthreads();

    // sort by pred index via rank counting (values distinct)
    for (int t = lane; t < NTGT; t += 64) {
        int myv = g2p[t];
        int rank = 0;
        for (int l = 0; l < NTGT; ++l) rank += (g2p[l] < myv) ? 1 : 0;
        out[b * 2 * NTGT + rank] = myv;          // index_i: sorted pred indices
        out[b * 2 * NTGT + NTGT + rank] = t;     // index_j: gt index (argsort)
    }
}

extern "C" void kernel_launch(void* const* d_in, const int* in_sizes, int n_in,
                              void* d_out, int out_size, void* d_ws, size_t ws_size,
                              hipStream_t stream) {
    const float* outputs = (const float*)d_in[0];  // [32, 512, 768]
    const float* targets = (const float*)d_in[1];  // [32, 200, 768]
    int* out = (int*)d_out;                        // [32, 2, 200] int32

    float* cost   = (float*)d_ws;                         // [32][200][512]
    float* no_arr = cost + (size_t)BATCH * NTGT * NPRED;  // [32*512]
    float* nt_arr = no_arr + (size_t)BATCH * NPRED;       // [32*200]

    norms_kernel<<<BATCH * (NPRED + NTGT), 64, 0, stream>>>(outputs, targets,
                                                            no_arr, nt_arr);
    cost_kernel<<<512, 256, 0, stream>>>(outputs, targets, no_arr, nt_arr, cost);
    lap_kernel<<<BATCH, 64, 0, stream>>>(cost, out);
}